// Round 1
// baseline (912.441 us; speedup 1.0000x reference)
//
#include <hip/hip_runtime.h>

// Char-LSTM: VOCAB=100, E=32, H=64, N=65536 words, MAX_LEN=16.
// Strategy:
//   prep_xt:  xt4[ch][j][4] = b_ih + b_hh + emb[ch] @ W_ih.T   (100x256 table, kills E-part)
//   prep_w4:  W4[k][j][4]   = W_hh rearranged so lane j's 4 gate weights at depth k are a float4
//   lstm_main: ONE WAVE PER WORD. lane j owns hidden unit j (h, c in 2 VGPRs).
//     All of lane j's W_hh slice lives in 256 VGPRs (float4 wv[64]).
//     h[k] broadcast via v_readlane (k = unrolled constant -> SGPR operand to v_fmac).
//     t-loop bound = lengths[w] (wave-uniform -> free length skipping, no divergence).

#define VOCAB 100
#define E     32
#define H     64
#define NW    65536
#define MAXL  16

__global__ void prep_w4(const float* __restrict__ Whh, float* __restrict__ W4) {
    int tid = blockIdx.x * 256 + threadIdx.x;          // 0..16383
    int k = tid >> 8, j = (tid >> 2) & 63, q = tid & 3;
    // gate row (torch order i,f,g,o): row = q*64 + j ; W_hh is [256][64] row-major
    W4[tid] = Whh[((q << 6) + j) * H + k];
}

__global__ void prep_xt(const float* __restrict__ emb, const float* __restrict__ Wih,
                        const float* __restrict__ bih, const float* __restrict__ bhh,
                        float* __restrict__ xt4) {
    int ch = blockIdx.x;                                // 0..99
    int j = threadIdx.x >> 2, q = threadIdx.x & 3;
    int g = (q << 6) + j;
    float acc = bih[g] + bhh[g];
    const float* er = emb + ch * E;
    const float* wr = Wih + g * E;
    #pragma unroll
    for (int e = 0; e < E; ++e) acc = fmaf(er[e], wr[e], acc);
    xt4[((ch << 6) + j) * 4 + q] = acc;
}

__device__ __forceinline__ float sigmoid_f(float x) {
    return __fdividef(1.f, 1.f + __expf(-x));
}
__device__ __forceinline__ float tanh_f(float x) {
    // 1 - 2/(e^{2x}+1); saturates correctly at +-1 for large |x|
    return 1.f - __fdividef(2.f, __expf(2.f * x) + 1.f);
}

__launch_bounds__(256, 1)
__global__ void lstm_main(const float* __restrict__ W4, const float* __restrict__ xt4,
                          const int* __restrict__ chars, const int* __restrict__ lengths,
                          float* __restrict__ out) {
    const int lane = threadIdx.x & 63;
    const int wave = (blockIdx.x * blockDim.x + threadIdx.x) >> 6;   // 0..8191

    // Load this lane's weight slice: wv[k] = (Wi, Wf, Wg, Wo) for (unit=lane, depth k).
    // Coalesced per k: lanes read consecutive float4s.
    float4 wv[64];
    #pragma unroll
    for (int k = 0; k < 64; ++k)
        wv[k] = *reinterpret_cast<const float4*>(W4 + (((k << 6) + lane) << 2));

    #pragma unroll 1
    for (int i = 0; i < 8; ++i) {                       // 8 words per wave
        const int w   = (wave << 3) + i;
        const int len = lengths[w];                     // wave-uniform
        const int* cw = chars + w * MAXL;
        float h = 0.f, c = 0.f;
        #pragma unroll 1
        for (int t = 0; t < len; ++t) {
            const int ch = cw[t];                       // wave-uniform -> s_load
            float4 acc = *reinterpret_cast<const float4*>(xt4 + (((ch << 6) + lane) << 2));
            #pragma unroll
            for (int k = 0; k < 64; ++k) {
                float hk = __int_as_float(__builtin_amdgcn_readlane(__float_as_int(h), k));
                acc.x = fmaf(wv[k].x, hk, acc.x);
                acc.y = fmaf(wv[k].y, hk, acc.y);
                acc.z = fmaf(wv[k].z, hk, acc.z);
                acc.w = fmaf(wv[k].w, hk, acc.w);
            }
            float ig = sigmoid_f(acc.x);
            float fg = sigmoid_f(acc.y);
            float gg = tanh_f(acc.z);
            float og = sigmoid_f(acc.w);
            c = fmaf(fg, c, ig * gg);
            h = og * tanh_f(c);
        }
        out[(w << 6) + lane] = h;                       // coalesced 256B per wave
    }
}

extern "C" void kernel_launch(void* const* d_in, const int* in_sizes, int n_in,
                              void* d_out, int out_size, void* d_ws, size_t ws_size,
                              hipStream_t stream) {
    const float* emb = (const float*)d_in[0];
    const float* Wih = (const float*)d_in[1];
    const float* Whh = (const float*)d_in[2];
    const float* bih = (const float*)d_in[3];
    const float* bhh = (const float*)d_in[4];
    const int* chars = (const int*)d_in[5];
    const int* lens  = (const int*)d_in[6];
    float* out = (float*)d_out;

    float* W4  = (float*)d_ws;                  // 16384 floats = 64 KB
    float* xt4 = (float*)d_ws + 16384;          // 25600 floats = 100 KB

    prep_w4<<<64, 256, 0, stream>>>(Whh, W4);
    prep_xt<<<VOCAB, 256, 0, stream>>>(emb, Wih, bih, bhh, xt4);

    // 8192 waves x 8 words = 65536 words; 2048 blocks of 256 threads (4 waves/block)
    lstm_main<<<2048, 256, 0, stream>>>(W4, xt4, chars, lens, out);
}

// Round 2
// 505.605 us; speedup vs baseline: 1.8047x; 1.8047x over previous
//
#include <hip/hip_runtime.h>

// Char-LSTM: VOCAB=100, E=32, H=64, N=65536 words, MAX_LEN=16.
// Round 2: round-1 evidence (VGPR=148, dur ~= L1-BW model) showed weights were
// reloaded from memory every k-step. Fix: weights in LDS, 8 words per wave to
// amortize each ds_read across 8 words, and counting-sort words by length so
// the 8 words in a wave share the same trip count (no lockstep waste).

#define VOCAB 100
#define E     32
#define H     64
#define NW    65536
#define MAXL  16

// ---------------- prep: tables ----------------
// W4[k][j][4] : (Wi,Wf,Wg,Wo) for hidden unit j at depth k (float4 per (k,j))
__global__ void prep_w4(const float* __restrict__ Whh, float* __restrict__ W4) {
    int tid = blockIdx.x * 256 + threadIdx.x;          // 0..16383
    int k = tid >> 8, j = (tid >> 2) & 63, q = tid & 3;
    W4[tid] = Whh[((q << 6) + j) * H + k];             // gate row = q*64 + j
}

// xt4[ch][j][4] = b_ih + b_hh + emb[ch] @ W_ih.T  (input-side GEMM folded into a table)
__global__ void prep_xt(const float* __restrict__ emb, const float* __restrict__ Wih,
                        const float* __restrict__ bih, const float* __restrict__ bhh,
                        float* __restrict__ xt4) {
    int ch = blockIdx.x;                                // 0..99
    int j = threadIdx.x >> 2, q = threadIdx.x & 3;
    int g = (q << 6) + j;
    float acc = bih[g] + bhh[g];
    const float* er = emb + ch * E;
    const float* wr = Wih + g * E;
    #pragma unroll
    for (int e = 0; e < E; ++e) acc = fmaf(er[e], wr[e], acc);
    xt4[((ch << 6) + j) * 4 + q] = acc;
}

// ---------------- counting sort by length (deterministic, no global atomics) ----------------
__global__ void k_hist(const int* __restrict__ lengths, int* __restrict__ bh) {
    __shared__ int h[16];
    if (threadIdx.x < 16) h[threadIdx.x] = 0;
    __syncthreads();
    int w = blockIdx.x * 256 + threadIdx.x;
    atomicAdd(&h[lengths[w] - 1], 1);
    __syncthreads();
    if (threadIdx.x < 16) bh[blockIdx.x * 16 + threadIdx.x] = h[threadIdx.x];
}

__global__ void k_bases(const int* __restrict__ bh, int* __restrict__ bases) {
    __shared__ int tot[16];
    __shared__ int bb[16];
    int b = threadIdx.x;                                // 64 threads, first 16 active
    if (b < 16) { int s = 0; for (int blk = 0; blk < 256; ++blk) s += bh[blk * 16 + b]; tot[b] = s; }
    __syncthreads();
    if (threadIdx.x == 0) { int a = 0; for (int i = 0; i < 16; ++i) { bb[i] = a; a += tot[i]; } }
    __syncthreads();
    if (b < 16) { int a = bb[b]; for (int blk = 0; blk < 256; ++blk) { bases[blk * 16 + b] = a; a += bh[blk * 16 + b]; } }
}

__global__ void k_scatter(const int* __restrict__ lengths, const int* __restrict__ bases,
                          int* __restrict__ perm) {
    __shared__ int h[16];
    if (threadIdx.x < 16) h[threadIdx.x] = 0;
    __syncthreads();
    int w = blockIdx.x * 256 + threadIdx.x;
    int b = lengths[w] - 1;
    int r = atomicAdd(&h[b], 1);                        // rank within (block,bucket)
    perm[bases[blockIdx.x * 16 + b] + r] = w;
}

// ---------------- main LSTM ----------------
__device__ __forceinline__ float sigmoid_f(float x) {
    return __fdividef(1.f, 1.f + __expf(-x));
}
__device__ __forceinline__ float tanh_f(float x) {
    return 1.f - __fdividef(2.f, __expf(2.f * x) + 1.f);   // saturates at +-1
}

__global__ __launch_bounds__(512, 4) void lstm_main(
    const float* __restrict__ W4, const float* __restrict__ xt4,
    const int* __restrict__ chars, const int* __restrict__ lengths,
    const int* __restrict__ perm, float* __restrict__ out)
{
    __shared__ float4 ws4[4096];                        // 64 KB: [k][j] float4
    {
        const float4* g = reinterpret_cast<const float4*>(W4);
        for (int i = threadIdx.x; i < 4096; i += 512) ws4[i] = g[i];
    }
    __syncthreads();

    const int lane = threadIdx.x & 63;
    const int wave = (blockIdx.x * 512 + threadIdx.x) >> 6;   // 0..8191
    const int base = wave << 3;                               // 8 sorted words per wave

    int wid[8], len[8];
    int maxl = 0;
    #pragma unroll
    for (int i = 0; i < 8; ++i) {
        wid[i] = __builtin_amdgcn_readfirstlane(perm[base + i]);   // wave-uniform -> SGPR
        len[i] = __builtin_amdgcn_readfirstlane(lengths[wid[i]]);
        maxl = (len[i] > maxl) ? len[i] : maxl;
    }

    float h[8], c[8];
    #pragma unroll
    for (int i = 0; i < 8; ++i) { h[i] = 0.f; c[i] = 0.f; }

    #pragma unroll 1
    for (int t = 0; t < maxl; ++t) {
        float4 acc[8];
        #pragma unroll
        for (int i = 0; i < 8; ++i) {
            int ch = chars[wid[i] * MAXL + t];                     // scalar load (uniform)
            acc[i] = *reinterpret_cast<const float4*>(xt4 + (((ch << 6) + lane) << 2));
        }
        #pragma unroll 16
        for (int k = 0; k < 64; ++k) {
            float4 w = ws4[(k << 6) + lane];                       // 1 ds_read_b128 serves 8 words
            #pragma unroll
            for (int i = 0; i < 8; ++i) {
                float hk = __int_as_float(__builtin_amdgcn_readlane(__float_as_int(h[i]), k));
                acc[i].x = fmaf(w.x, hk, acc[i].x);
                acc[i].y = fmaf(w.y, hk, acc[i].y);
                acc[i].z = fmaf(w.z, hk, acc[i].z);
                acc[i].w = fmaf(w.w, hk, acc[i].w);
            }
        }
        #pragma unroll
        for (int i = 0; i < 8; ++i) {
            if (t < len[i]) {                                      // uniform (SGPR) condition
                float ig = sigmoid_f(acc[i].x);
                float fg = sigmoid_f(acc[i].y);
                float gg = tanh_f(acc[i].z);
                float og = sigmoid_f(acc[i].w);
                c[i] = fmaf(fg, c[i], ig * gg);
                h[i] = og * tanh_f(c[i]);
            }
        }
    }
    #pragma unroll
    for (int i = 0; i < 8; ++i) out[(wid[i] << 6) + lane] = h[i];  // 256B coalesced per word
}

extern "C" void kernel_launch(void* const* d_in, const int* in_sizes, int n_in,
                              void* d_out, int out_size, void* d_ws, size_t ws_size,
                              hipStream_t stream) {
    const float* emb = (const float*)d_in[0];
    const float* Wih = (const float*)d_in[1];
    const float* Whh = (const float*)d_in[2];
    const float* bih = (const float*)d_in[3];
    const float* bhh = (const float*)d_in[4];
    const int* chars = (const int*)d_in[5];
    const int* lens  = (const int*)d_in[6];
    float* out = (float*)d_out;

    float* W4   = (float*)d_ws;                  // 16384 f = 64 KB (16B aligned)
    float* xt4  = W4 + 16384;                    // 25600 f = 100 KB
    int*   bh   = (int*)(xt4 + 25600);           // 256*16
    int*   bas  = bh + 4096;                     // 256*16
    int*   perm = bas + 4096;                    // 65536

    prep_w4<<<64, 256, 0, stream>>>(Whh, W4);
    prep_xt<<<VOCAB, 256, 0, stream>>>(emb, Wih, bih, bhh, xt4);
    k_hist<<<256, 256, 0, stream>>>(lens, bh);
    k_bases<<<1, 64, 0, stream>>>(bh, bas);
    k_scatter<<<256, 256, 0, stream>>>(lens, bas, perm);

    // 1024 blocks x 512 threads = 8192 waves x 8 words = 65536 words
    lstm_main<<<1024, 512, 0, stream>>>(W4, xt4, chars, lens, perm, out);
}

// Round 3
// 192.509 us; speedup vs baseline: 4.7397x; 2.6264x over previous
//
#include <hip/hip_runtime.h>
#include <hip/hip_bf16.h>

// Char-LSTM via MFMA: per step, G^T[256][16] = Whh_bf16[256][64] x H^T_bf16[64][16],
// C-init = fp32 xt table. 16 sorted words per wave-group; weights in 128 VGPRs;
// H relayout via swizzled per-wave LDS bounce (no barrier).

#define VOCAB 100
#define E     32
#define NH    64
#define NW    65536
#define MAXL  16
#define NGRP  4096   // NW/16

typedef __bf16 bf16x8 __attribute__((ext_vector_type(8)));
typedef float  f32x4  __attribute__((ext_vector_type(4)));
typedef unsigned short ushort_t;
typedef unsigned int uint_t;

__device__ __forceinline__ ushort_t f2bf(float x) {
    union { __hip_bfloat16 b; ushort_t u; } cv;
    cv.b = __float2bfloat16(x);
    return cv.u;
}
__device__ __forceinline__ float sigm(float x) {
    return __fdividef(1.f, 1.f + __expf(-x));
}
__device__ __forceinline__ float tanh_(float x) {
    return 1.f - __fdividef(2.f, __expf(2.f * x) + 1.f);  // saturates at +-1
}

// ---- fused prep: xtab [100][256] f32, Wb [256][64] bf16, block-hist [256][16] ----
__global__ void prep_fused(const float* __restrict__ emb, const float* __restrict__ Wih,
                           const float* __restrict__ Whh, const float* __restrict__ bih,
                           const float* __restrict__ bhh, const int* __restrict__ lengths,
                           float* __restrict__ xtab, ushort_t* __restrict__ Wb,
                           int* __restrict__ bh) {
    int bid = blockIdx.x;
    if (bid < VOCAB) {                         // xtab row: g = q*64+u (torch row order)
        int ch = bid, g = threadIdx.x;
        float acc = bih[g] + bhh[g];
        const float* er = emb + ch * E;
        const float* wr = Wih + g * E;
        #pragma unroll
        for (int e = 0; e < E; ++e) acc = fmaf(er[e], wr[e], acc);
        xtab[ch * 256 + g] = acc;
    } else if (bid < VOCAB + 64) {             // Wb = bf16(Whh), same [256][64] layout
        int i = (bid - VOCAB) * 256 + threadIdx.x;
        Wb[i] = f2bf(Whh[i]);
    } else {                                   // per-block length histogram
        int blk = bid - (VOCAB + 64);          // 0..255
        __shared__ int h[16];
        if (threadIdx.x < 16) h[threadIdx.x] = 0;
        __syncthreads();
        atomicAdd(&h[lengths[blk * 256 + threadIdx.x] - 1], 1);
        __syncthreads();
        if (threadIdx.x < 16) bh[blk * 16 + threadIdx.x] = h[threadIdx.x];
    }
}

__global__ void k_bases(const int* __restrict__ bh, int* __restrict__ bases) {
    __shared__ int tot[16], bb[16];
    int b = threadIdx.x;
    if (b < 16) { int s = 0; for (int blk = 0; blk < 256; ++blk) s += bh[blk * 16 + b]; tot[b] = s; }
    __syncthreads();
    if (threadIdx.x == 0) { int a = 0; for (int i = 0; i < 16; ++i) { bb[i] = a; a += tot[i]; } }
    __syncthreads();
    if (b < 16) { int a = bb[b]; for (int blk = 0; blk < 256; ++blk) { bases[blk * 16 + b] = a; a += bh[blk * 16 + b]; } }
}

__global__ void k_scatter(const int* __restrict__ lengths, const int* __restrict__ bases,
                          int* __restrict__ perm) {
    __shared__ int h[16];
    if (threadIdx.x < 16) h[threadIdx.x] = 0;
    __syncthreads();
    int w = blockIdx.x * 256 + threadIdx.x;
    int b = lengths[w] - 1;
    int r = atomicAdd(&h[b], 1);
    perm[bases[blockIdx.x * 16 + b] + r] = w;
}

// ---- main ----
__global__ __launch_bounds__(256, 2) void lstm_main(
    const ushort_t* __restrict__ Wb, const float* __restrict__ xtab,
    const int* __restrict__ chars, const int* __restrict__ lengths,
    const int* __restrict__ perm, float* __restrict__ out)
{
    __shared__ __align__(16) char Hlds_all[4][2048];
    char* Hbase = Hlds_all[threadIdx.x >> 6];

    const int lane = threadIdx.x & 63;
    const int w  = lane & 15;                 // word slot in group (also MFMA N-col)
    const int lq = lane >> 4;                 // lane quad
    const int wave = (blockIdx.x << 2) + (threadIdx.x >> 6);   // 0..2047

    // A-fragments: Whh bf16, tile m covers gates m*16..m*16+15; lane row = w.
    // k positions: consistent contiguous convention for A and B (dot product is
    // invariant under any consistent K permutation).
    bf16x8 a[16][2];
    #pragma unroll
    for (int m = 0; m < 16; ++m)
        #pragma unroll
        for (int kh = 0; kh < 2; ++kh)
            a[m][kh] = *reinterpret_cast<const bf16x8*>(Wb + ((m * 16 + w) * 64 + kh * 32 + lq * 8));

    // Swizzled LDS offsets (per-thread constants). H row = 128B; byte = w*128 + ((u*2)^((w&7)<<4)).
    const int sw = (w & 7) << 4;
    const int base_w = w * 128;
    int wr_off[4], rd_off[2];
    #pragma unroll
    for (int b = 0; b < 4; ++b) wr_off[b] = base_w + ((b * 32 + lq * 8) ^ sw);
    #pragma unroll
    for (int kh = 0; kh < 2; ++kh) rd_off[kh] = base_w + ((kh * 64 + lq * 16) ^ sw);

    #pragma unroll 1
    for (int gi = 0; gi < 2; ++gi) {
        const int grp = gi ? (NGRP - 1 - wave) : wave;    // pair short+long groups
        const int wid = perm[grp * 16 + w];
        const int len = lengths[wid];
        const int maxl = __builtin_amdgcn_readlane(len, 15);  // sorted ascending
        const int* chp = chars + wid * MAXL;

        float hreg[4][4], creg[4][4];
        #pragma unroll
        for (int b = 0; b < 4; ++b)
            #pragma unroll
            for (int r = 0; r < 4; ++r) { hreg[b][r] = 0.f; creg[b][r] = 0.f; }

        int ch = chp[0];
        const float* xrow = xtab + ch * 256;
        f32x4 xtb[2][4];
        #pragma unroll
        for (int q = 0; q < 4; ++q)           // tiles q*4+0 for b=0
            xtb[0][q] = *reinterpret_cast<const f32x4*>(xrow + (q * 4 + 0) * 16 + lq * 4);

        #pragma unroll 1
        for (int t = 0; t < maxl; ++t) {
            const int tn = (t + 1 < maxl) ? t + 1 : t;
            const int ch_nxt = chp[tn];                       // prefetch next char
            const float* xrow_n = xtab + ch_nxt * 256;

            bf16x8 B0, B1;
            if (t > 0) {
                asm volatile("s_waitcnt lgkmcnt(0)" ::: "memory");  // prev-step H writes
                B0 = *reinterpret_cast<const bf16x8*>(Hbase + rd_off[0]);
                B1 = *reinterpret_cast<const bf16x8*>(Hbase + rd_off[1]);
            }
            const bool act = (t < len);                       // per-lane (word w) mask

            #pragma unroll
            for (int b = 0; b < 4; ++b) {
                if (b < 3) {                                  // prefetch xt tiles for b+1
                    #pragma unroll
                    for (int q = 0; q < 4; ++q)
                        xtb[(b + 1) & 1][q] = *reinterpret_cast<const f32x4*>(xrow + (q * 4 + b + 1) * 16 + lq * 4);
                } else {                                      // prefetch next step's b=0
                    #pragma unroll
                    for (int q = 0; q < 4; ++q)
                        xtb[0][q] = *reinterpret_cast<const f32x4*>(xrow_n + q * 64 + lq * 4);
                }
                f32x4 d[4];
                #pragma unroll
                for (int q = 0; q < 4; ++q) d[q] = xtb[b & 1][q];
                if (t > 0) {
                    #pragma unroll
                    for (int q = 0; q < 4; ++q) {
                        d[q] = __builtin_amdgcn_mfma_f32_16x16x32_bf16(a[q * 4 + b][0], B0, d[q], 0, 0, 0);
                        d[q] = __builtin_amdgcn_mfma_f32_16x16x32_bf16(a[q * 4 + b][1], B1, d[q], 0, 0, 0);
                    }
                }
                // lane-local activations: unit u = b*16 + lq*4 + r, word w
                #pragma unroll
                for (int r = 0; r < 4; ++r) {
                    float ig = sigm(d[0][r]);
                    float fg = sigm(d[1][r]);
                    float gg = tanh_(d[2][r]);
                    float og = sigm(d[3][r]);
                    float cn = fmaf(fg, creg[b][r], ig * gg);
                    float hn = og * tanh_(cn);
                    creg[b][r] = act ? cn : creg[b][r];
                    hreg[b][r] = act ? hn : hreg[b][r];
                }
                // write h (bf16) to LDS for next step's B-fragments
                uint_t lo = (uint_t)f2bf(hreg[b][0]) | ((uint_t)f2bf(hreg[b][1]) << 16);
                uint_t hi = (uint_t)f2bf(hreg[b][2]) | ((uint_t)f2bf(hreg[b][3]) << 16);
                *reinterpret_cast<uint2*>(Hbase + wr_off[b]) = make_uint2(lo, hi);
            }
            ch = ch_nxt;
            xrow = xrow_n;
        }

        #pragma unroll
        for (int b = 0; b < 4; ++b) {
            f32x4 o;
            #pragma unroll
            for (int r = 0; r < 4; ++r) o[r] = hreg[b][r];
            *reinterpret_cast<f32x4*>(out + wid * 64 + b * 16 + lq * 4) = o;
        }
    }
}

extern "C" void kernel_launch(void* const* d_in, const int* in_sizes, int n_in,
                              void* d_out, int out_size, void* d_ws, size_t ws_size,
                              hipStream_t stream) {
    const float* emb = (const float*)d_in[0];
    const float* Wih = (const float*)d_in[1];
    const float* Whh = (const float*)d_in[2];
    const float* bih = (const float*)d_in[3];
    const float* bhh = (const float*)d_in[4];
    const int* chars = (const int*)d_in[5];
    const int* lens  = (const int*)d_in[6];
    float* out = (float*)d_out;

    float*    xtab = (float*)d_ws;            // 25600 f32 = 100 KB
    ushort_t* Wb   = (ushort_t*)(xtab + 25600); // 16384 bf16 = 32 KB
    int*      bh   = (int*)(Wb + 16384);      // 256*16
    int*      bas  = bh + 4096;               // 256*16
    int*      perm = bas + 4096;              // 65536

    prep_fused<<<VOCAB + 64 + 256, 256, 0, stream>>>(emb, Wih, Whh, bih, bhh, lens, xtab, Wb, bh);
    k_bases<<<1, 64, 0, stream>>>(bh, bas);
    k_scatter<<<256, 256, 0, stream>>>(lens, bas, perm);

    // 512 blocks x 4 waves = 2048 waves; wave i does groups i and 4095-i
    lstm_main<<<512, 256, 0, stream>>>(Wb, xtab, chars, lens, perm, out);
}